// Round 11
// baseline (494.839 us; speedup 1.0000x reference)
//
#include <hip/hip_runtime.h>

typedef __attribute__((ext_vector_type(8))) short short8;
typedef __attribute__((ext_vector_type(4))) float floatx4;
typedef __attribute__((ext_vector_type(4))) unsigned short ushortx4;

// ---------- bf16 helpers ----------
__device__ __forceinline__ float bf2f(unsigned short u) {
  union { unsigned int i; float f; } v; v.i = ((unsigned int)u) << 16; return v.f;
}
__device__ __forceinline__ unsigned short f2bf(float f) {
  union { float f; unsigned int i; } v; v.f = f;
  unsigned int x = v.i + 0x7fffu + ((v.i >> 16) & 1u);
  return (unsigned short)(x >> 16);
}
__device__ __forceinline__ float loadE(const void* p, size_t i, int f) {
  return f ? ((const float*)p)[i] : bf2f(((const unsigned short*)p)[i]);
}
__device__ __forceinline__ uint4 packbf(float4 a, float4 b) {
  union { unsigned short u[8]; uint4 v; } p;
  p.u[0] = f2bf(a.x); p.u[1] = f2bf(a.y); p.u[2] = f2bf(a.z); p.u[3] = f2bf(a.w);
  p.u[4] = f2bf(b.x); p.u[5] = f2bf(b.y); p.u[6] = f2bf(b.z); p.u[7] = f2bf(b.w);
  return p.v;
}

// async global->LDS, 16B per lane. LDS dest = wave-uniform base + lane*16.
__device__ __forceinline__ void gl16(const unsigned short* g, unsigned short* l) {
  __builtin_amdgcn_global_load_lds(
      (const __attribute__((address_space(1))) void*)g,
      (__attribute__((address_space(3))) void*)l, 16, 0, 0);
}

// ---------- dtype detect ----------
__global__ void detect_kernel(const unsigned int* __restrict__ probe, int* __restrict__ flag) {
  if (threadIdx.x == 0 && blockIdx.x == 0) *flag = (probe[0] == 0x3F800000u) ? 1 : 0;
}

// ---------- weight conversion -> bf16, block-uniform segments ----------
struct CArgs {
  const void* in[12];
  unsigned short* out[12];
  unsigned int cum[12];  // cumulative chunk counts (chunk = 8 elems), sentinel-filled
};
__global__ __launch_bounds__(256) void convw_kernel(CArgs a, const int* __restrict__ flagp) {
  const int flag = *flagp;
  int bc = blockIdx.x * 2048;  // first chunk of this block
  int s = 0;
  while (bc >= (int)a.cum[s]) ++s;
  int base = s ? (int)a.cum[s - 1] : 0;
  size_t e0 = ((size_t)(bc - base) + threadIdx.x) * 8;
  if (flag) {
    const float* in = (const float*)a.in[s];
    unsigned short* out = a.out[s];
    float4 v0[8], v1[8];
    #pragma unroll
    for (int k = 0; k < 8; ++k) {
      size_t e = e0 + (size_t)k * 2048;
      v0[k] = *(const float4*)(in + e);
      v1[k] = *(const float4*)(in + e + 4);
    }
    #pragma unroll
    for (int k = 0; k < 8; ++k)
      *(uint4*)(out + e0 + (size_t)k * 2048) = packbf(v0[k], v1[k]);
  } else {
    const unsigned short* in = (const unsigned short*)a.in[s];
    unsigned short* out = a.out[s];
    #pragma unroll
    for (int k = 0; k < 8; ++k) {
      size_t e = e0 + (size_t)k * 2048;
      *(uint4*)(out + e) = *(const uint4*)(in + e);
    }
  }
}

// ---------- zero d_out (fallback path only) ----------
__global__ __launch_bounds__(256) void zero_kernel(void* __restrict__ out, int out_elems,
                                                   const int* __restrict__ flagp) {
  int limit = (*flagp) ? (out_elems >> 2) : (out_elems >> 3);  // uint4 chunks
  int i = blockIdx.x * 256 + threadIdx.x;
  if (i < limit) ((uint4*)out)[i] = make_uint4(0, 0, 0, 0);
}

// ---------- P5 split-K reduce: d_out = sum_z part[z] + bias + res(mid) ----------
__global__ __launch_bounds__(256) void reduce_kernel(const float* __restrict__ part,
                                                     const unsigned short* __restrict__ mid,
                                                     const void* __restrict__ b1,   // p1_b2 (x rows)
                                                     const void* __restrict__ b2,   // p2_b2 (c rows)
                                                     float* __restrict__ out,
                                                     const int* __restrict__ flagp) {
  if (!*flagp) return;
  const size_t TD = 2097152, LD = (size_t)1536 * 1024, SD = (size_t)512 * 1024;
  size_t i = ((size_t)blockIdx.x * 256 + threadIdx.x) * 4;
  if (i >= TD) return;
  float4 v  = *(const float4*)(part + i);
  float4 v1 = *(const float4*)(part + TD + i);
  float4 v2 = *(const float4*)(part + 2 * TD + i);
  float4 v3 = *(const float4*)(part + 3 * TD + i);
  v.x += v1.x + v2.x + v3.x;
  v.y += v1.y + v2.y + v3.y;
  v.z += v1.z + v2.z + v3.z;
  v.w += v1.w + v2.w + v3.w;
  int col = (int)(i & 1023);
  const float* bias = (const float*)((i < LD) ? b1 : b2);
  size_t ri = (i < LD) ? (SD + i) : (i - LD);
  v.x += bias[col + 0] + bf2f(mid[ri + 0]);
  v.y += bias[col + 1] + bf2f(mid[ri + 1]);
  v.z += bias[col + 2] + bf2f(mid[ri + 2]);
  v.w += bias[col + 3] + bf2f(mid[ri + 3]);
  *(float4*)(out + i) = v;
}

// ---------- P2 split-K reduce: mid = bf16( sum_z part[z] + bias + external res ) ----------
__global__ __launch_bounds__(256) void reduce_mid_kernel(const float* __restrict__ part,
                                                         const void* __restrict__ cres,
                                                         const void* __restrict__ xres,
                                                         const float* __restrict__ b_c,
                                                         const float* __restrict__ b_x,
                                                         unsigned short* __restrict__ mid,
                                                         const int* __restrict__ flagp) {
  if (!*flagp) return;  // bf16 path: GEMM slice 0 wrote mid directly
  const size_t TD = 2097152;
  size_t i = ((size_t)blockIdx.x * 256 + threadIdx.x) * 4;
  if (i >= TD) return;
  float4 v  = *(const float4*)(part + i);
  float4 v1 = *(const float4*)(part + TD + i);
  float4 v2 = *(const float4*)(part + 2 * TD + i);
  float4 v3 = *(const float4*)(part + 3 * TD + i);
  v.x += v1.x + v2.x + v3.x;
  v.y += v1.y + v2.y + v3.y;
  v.z += v1.z + v2.z + v3.z;
  v.w += v1.w + v2.w + v3.w;
  int row = (int)(i >> 10), col = (int)(i & 1023);
  const float* bias = (row < 512) ? b_c : b_x;
  const float* res = (row < 512)
      ? (const float*)cres + ((size_t)row << 10) + col
      : (const float*)xres + ((size_t)(row - 512) << 10) + col;
  float4 rv = *(const float4*)res;
  float4 bv = *(const float4*)(bias + col);
  ushortx4 o;
  o[0] = f2bf(v.x + bv.x + rv.x);
  o[1] = f2bf(v.y + bv.y + rv.y);
  o[2] = f2bf(v.z + bv.z + rv.z);
  o[3] = f2bf(v.w + bv.w + rv.w);
  *(ushortx4*)(mid + i) = o;
}

// ---------- LayerNorm over both external inputs -> unified bf16 (c rows first) ----------
__global__ __launch_bounds__(256) void ln_ext_kernel(const void* __restrict__ cin,
                                                     const void* __restrict__ xin,
                                                     unsigned short* __restrict__ out,
                                                     const int* __restrict__ flagp) {
  const int D = 1024, S = 512;
  const int flag = *flagp;
  int row = blockIdx.x;
  const void* src = (row < S) ? cin : xin;
  size_t rb = (size_t)(row < S ? row : row - S) * D;
  int base = threadIdx.x * 4;
  float x0 = loadE(src, rb + base + 0, flag);
  float x1 = loadE(src, rb + base + 1, flag);
  float x2 = loadE(src, rb + base + 2, flag);
  float x3 = loadE(src, rb + base + 3, flag);
  float s1 = x0 + x1 + x2 + x3;
  float s2 = x0 * x0 + x1 * x1 + x2 * x2 + x3 * x3;
  for (int off = 32; off; off >>= 1) {
    s1 += __shfl_down(s1, off, 64);
    s2 += __shfl_down(s2, off, 64);
  }
  __shared__ float red[8];
  int wid = threadIdx.x >> 6;
  if ((threadIdx.x & 63) == 0) { red[wid] = s1; red[4 + wid] = s2; }
  __syncthreads();
  s1 = red[0] + red[1] + red[2] + red[3];
  s2 = red[4] + red[5] + red[6] + red[7];
  float mean = s1 * (1.0f / D);
  float var = s2 * (1.0f / D) - mean * mean;
  float inv = rsqrtf(var + 1e-6f);
  unsigned short* dst = out + (size_t)row * D + base;
  dst[0] = f2bf((x0 - mean) * inv);
  dst[1] = f2bf((x1 - mean) * inv);
  dst[2] = f2bf((x2 - mean) * inv);
  dst[3] = f2bf((x3 - mean) * inv);
}

// ---------- LayerNorm over internal bf16 mid; split outputs ----------
__global__ __launch_bounds__(256) void ln_mid_kernel(const unsigned short* __restrict__ in,
                                                     unsigned short* __restrict__ outc,
                                                     unsigned short* __restrict__ outx) {
  const int D = 1024, S = 512;
  int row = blockIdx.x;
  const unsigned short* src = in + (size_t)row * D;
  int base = threadIdx.x * 4;
  float x0 = bf2f(src[base + 0]);
  float x1 = bf2f(src[base + 1]);
  float x2 = bf2f(src[base + 2]);
  float x3 = bf2f(src[base + 3]);
  float s1 = x0 + x1 + x2 + x3;
  float s2 = x0 * x0 + x1 * x1 + x2 * x2 + x3 * x3;
  for (int off = 32; off; off >>= 1) {
    s1 += __shfl_down(s1, off, 64);
    s2 += __shfl_down(s2, off, 64);
  }
  __shared__ float red[8];
  int wid = threadIdx.x >> 6;
  if ((threadIdx.x & 63) == 0) { red[wid] = s1; red[4 + wid] = s2; }
  __syncthreads();
  s1 = red[0] + red[1] + red[2] + red[3];
  s2 = red[4] + red[5] + red[6] + red[7];
  float mean = s1 * (1.0f / D);
  float var = s2 * (1.0f / D) - mean * mean;
  float inv = rsqrtf(var + 1e-6f);
  unsigned short* dst = (row < S ? outc + (size_t)row * D : outx + (size_t)(row - S) * D) + base;
  dst[0] = f2bf((x0 - mean) * inv);
  dst[1] = f2bf((x1 - mean) * inv);
  dst[2] = f2bf((x2 - mean) * inv);
  dst[3] = f2bf((x3 - mean) * inv);
}

// ---------- multi-descriptor GEMM (round-9 structure) ----------
struct GArgs {
  const unsigned short* A[4];
  const void* B[4];
  const void* bias[4];
  const void* res[4];
  void* C[4];
  unsigned long long oo[4];
  int mcum[4];  // cumulative m-tile counts
  int N[4];
  int K;
  int nd;
  int tmask;
  float* part;  // split-K partial base (OUT_MODE 3), slice stride 2048*1024
};

#define BAR() asm volatile("s_waitcnt lgkmcnt(0)\n\ts_barrier" ::: "memory")
#define FBAR() asm volatile("s_waitcnt vmcnt(0) lgkmcnt(0)\n\ts_barrier" ::: "memory")
#define CBAR4() asm volatile("s_waitcnt vmcnt(4) lgkmcnt(0)\n\ts_barrier" ::: "memory")

template <int RES_MODE, int OUT_MODE, int SPLITK, int BBF16>
__global__ __launch_bounds__(256) void gemm_kernel(GArgs g, const int* __restrict__ flagp) {
  const int flag = *flagp;
  int by = blockIdx.y;
  int d = 0;
  while (d < g.nd - 1 && by >= g.mcum[d]) ++d;
  int mbase = (d == 0) ? 0 : g.mcum[d - 1];
  const int m0 = (by - mbase) * 128;
  const int N = g.N[d];
  const int n0 = blockIdx.x * 128;
  if (n0 >= N) return;  // block-uniform
  const int K = g.K;
  int kbeg = 0, kend = K;
  if (SPLITK > 1) {
    if (!flag) {
      if (blockIdx.z != 0) return;
    } else {
      int kl = K / SPLITK;
      kbeg = blockIdx.z * kl;
      kend = kbeg + kl;
    }
  }
  const int nt = (kend - kbeg) >> 5;

  constexpr int NBUF = BBF16 ? 3 : 2;
  constexpr int BSTRIDE = BBF16 ? 4096 : 5120;
  __shared__ __align__(16) unsigned short sA[NBUF * BSTRIDE];
  __shared__ __align__(16) unsigned short sB[NBUF * BSTRIDE];

  const int tid = threadIdx.x;
  const int lane = tid & 63;
  const int wave = tid >> 6;
  const int wm = (wave >> 1) * 64, wn = (wave & 1) * 64;
  const int srow = tid >> 2;
  const int scol = BBF16 ? ((((tid & 3) ^ ((tid >> 3) & 3))) * 8) : ((tid & 3) * 8);
  const unsigned short* Ag0 = g.A[d] + (size_t)(m0 + srow) * K + kbeg + scol;
  const unsigned short* Ag1 = Ag0 + (size_t)64 * K;
  const unsigned short* Bh0 = (const unsigned short*)g.B[d] + (size_t)(n0 + srow) * K + kbeg + scol;
  const unsigned short* Bh1 = Bh0 + (size_t)64 * K;

  const int fr = lane & 15;
  const int rdo = BBF16 ? ((((lane >> 4) ^ ((fr >> 1) & 3))) * 8) : ((lane >> 4) * 8);
  constexpr int PITCH = BBF16 ? 32 : 40;
  floatx4 acc[4][4] = {};
  auto compute = [&](const unsigned short* as, const unsigned short* bs) {
    short8 af[4], bfr[4];
    #pragma unroll
    for (int i = 0; i < 4; ++i) {
      af[i]  = *(const short8*)(as + (wm + i * 16 + fr) * PITCH + rdo);
      bfr[i] = *(const short8*)(bs + (wn + i * 16 + fr) * PITCH + rdo);
    }
    #pragma unroll
    for (int mi = 0; mi < 4; ++mi)
      #pragma unroll
      for (int ni = 0; ni < 4; ++ni)
        acc[mi][ni] = __builtin_amdgcn_mfma_f32_16x16x32_bf16(af[mi], bfr[ni], acc[mi][ni], 0, 0, 0);
  };

  if (BBF16) {
    unsigned short* lA0 = sA + wave * 512;
    unsigned short* lA1 = lA0 + 2048;
    unsigned short* lB0 = sB + wave * 512;
    unsigned short* lB1 = lB0 + 2048;
    auto stage = [&](int buf, int kk) {
      int bo = buf * 4096;
      gl16(Ag0 + kk, lA0 + bo);
      gl16(Ag1 + kk, lA1 + bo);
      gl16(Bh0 + kk, lB0 + bo);
      gl16(Bh1 + kk, lB1 + bo);
    };
    stage(0, 0);
    if (nt > 1) stage(1, 32);
    int b = 0;  // t % 3
    for (int t = 0; t < nt; ++t) {
      if (t + 1 < nt) CBAR4();
      else            FBAR();
      int b2 = (b >= 1) ? b - 1 : 2;  // (t+2) % 3
      if (t + 2 < nt) stage(b2, (t + 2) * 32);
      compute(sA + b * 4096, sB + b * 4096);
      b = (b == 2) ? 0 : b + 1;
    }
  } else {
    const float* Bf0 = (const float*)g.B[d] + (size_t)(n0 + srow) * K + kbeg + scol;
    const float* Bf1 = Bf0 + (size_t)64 * K;
    const int wo0 = srow * 40 + scol;
    const int wo1 = wo0 + 64 * 40;
    uint4 ra0, ra1, rb0, rb1;
    auto load_tile = [&](int kk) {
      ra0 = *(const uint4*)(Ag0 + kk);
      ra1 = *(const uint4*)(Ag1 + kk);
      if (!flag) {
        rb0 = *(const uint4*)(Bh0 + kk);
        rb1 = *(const uint4*)(Bh1 + kk);
      } else {
        float4 x0 = *(const float4*)(Bf0 + kk), x1 = *(const float4*)(Bf0 + kk + 4);
        float4 y0 = *(const float4*)(Bf1 + kk), y1 = *(const float4*)(Bf1 + kk + 4);
        rb0 = packbf(x0, x1);
        rb1 = packbf(y0, y1);
      }
    };
    auto store_tile = [&](int buf) {
      unsigned short* sa = sA + buf * 5120;
      unsigned short* sb = sB + buf * 5120;
      *(uint4*)(sa + wo0) = ra0;
      *(uint4*)(sa + wo1) = ra1;
      *(uint4*)(sb + wo0) = rb0;
      *(uint4*)(sb + wo1) = rb1;
    };
    load_tile(0);
    store_tile(0);
    if (nt > 1) load_tile(32);
    BAR();
    for (int t = 0; t < nt; ++t) {
      if (t + 1 < nt) {
        store_tile((t + 1) & 1);
        if (t + 2 < nt) load_tile((t + 2) * 32);
      }
      compute(sA + (t & 1) * 5120, sB + (t & 1) * 5120);
      if (t + 1 < nt) BAR();
    }
  }

  const void* bias = g.bias[d];
  const void* res = g.res[d];
  void* C = g.C[d];
  const size_t oo = g.oo[d];
  const bool first = (SPLITK <= 1) || (blockIdx.z == 0) || !flag;
  const bool rawpart = (OUT_MODE == 3) && (flag != 0);
  const bool trans = (OUT_MODE == 0) && (((g.tmask) >> d) & 1);
  #pragma unroll
  for (int mi = 0; mi < 4; ++mi)
    #pragma unroll
    for (int ni = 0; ni < 4; ++ni) {
      int colb = n0 + wn + ni * 16 + (lane & 15);
      int rowb = m0 + wm + mi * 16 + (lane >> 4) * 4;
      if (trans) {
        ushortx4 o4;
        #pragma unroll
        for (int r = 0; r < 4; ++r) {
          float val = acc[mi][ni][r];
          if (bias) val += loadE(bias, (size_t)colb, flag);
          o4[r] = f2bf(val);
        }
        *(ushortx4*)((unsigned short*)C + (size_t)colb * 2048 + oo + rowb) = o4;
      } else {
        #pragma unroll
        for (int r = 0; r < 4; ++r) {
          int row = rowb + r;
          int col = colb;
          float val = acc[mi][ni][r];
          size_t off = (size_t)row * N + col;
          if (first && !rawpart) {
            if (bias) val += loadE(bias, (size_t)col, flag);
            if (RES_MODE == 1) val += loadE(res, off, flag);
            if (RES_MODE == 3) {
              float h1v = bf2f(((const unsigned short*)res)[off]);
              val = (h1v / (1.0f + __expf(-h1v))) * val;
            }
            if (RES_MODE == 4) val += bf2f(((const unsigned short*)res)[off]);
          }
          if (OUT_MODE == 0) {
            ((unsigned short*)C)[off] = f2bf(val);
          } else if (OUT_MODE == 3) {
            if (flag) g.part[(size_t)blockIdx.z * 2097152 + oo + off] = val;
            else      ((unsigned short*)C)[oo + off] = f2bf(val);
          } else {  // OUT_MODE == 2 (fallback)
            if (flag) {
              if (SPLITK > 1) atomicAdd((float*)C + oo + off, val);
              else            ((float*)C)[oo + off] = val;
            } else {
              ((unsigned short*)C)[oo + off] = f2bf(val);
            }
          }
        }
      }
    }
}

// ---------- per-(t,head) RMSNorm + RoPE, 4 heads/block, in place ----------
__global__ __launch_bounds__(256) void rmsrope_kernel(
    unsigned short* __restrict__ qk,
    const void* __restrict__ qn_c, const void* __restrict__ kn_c,
    const void* __restrict__ qn_x, const void* __restrict__ kn_x,
    const void* __restrict__ freqs, const int* __restrict__ flagp) {
  const int flag = *flagp;
  int t = blockIdx.x;
  int h = blockIdx.y * 4 + (threadIdx.x >> 6);
  int d = threadIdx.x & 63;
  unsigned short* qrow = qk + (size_t)t * 2048 + h * 64;
  unsigned short* krow = qrow + 1024;
  float q = bf2f(qrow[d]), k = bf2f(krow[d]);
  float qs = q * q, ks = k * k;
  for (int off = 32; off; off >>= 1) {
    qs += __shfl_xor(qs, off, 64);
    ks += __shfl_xor(ks, off, 64);
  }
  const void* qn = (t < 512) ? qn_c : qn_x;
  const void* kn = (t < 512) ? kn_c : kn_x;
  q = q * rsqrtf(qs * (1.0f / 64.0f) + 1e-6f) * loadE(qn, d, flag);
  k = k * rsqrtf(ks * (1.0f / 64.0f) + 1e-6f) * loadE(kn, d, flag);
  int j = d >> 1;
  float cv = loadE(freqs, (size_t)(t * 32 + j) * 2 + 0, flag);
  float sv = loadE(freqs, (size_t)(t * 32 + j) * 2 + 1, flag);
  float qo = __shfl_xor(q, 1, 64);
  float ko = __shfl_xor(k, 1, 64);
  float qn2, kn2;
  if ((d & 1) == 0) { qn2 = q * cv - qo * sv; kn2 = k * cv - ko * sv; }
  else              { qn2 = qo * sv + q * cv; kn2 = ko * sv + k * cv; }
  qrow[d] = f2bf(qn2);
  krow[d] = f2bf(kn2);
}

// ---------- MFMA flash attention, KV-split (flash-decoding style) ----------
// SPLIT=1: grid (32 qblk, 16 h, 4 slice); slice z covers KV tiles [8z, min(8z+8,ntiles)).
// Round-10 counters showed the old 512-block kernel was pinned by causal imbalance:
// the 32-tile diagonal blocks ran a ~4.3k-cyc/tile serial chain nearly alone
// (Occupancy 12%). Splitting caps the critical path at 8 tiles and gives 1280
// active blocks (5/CU). Groups with ns==1 (qblk<8) write y directly; others write
// (m,l,O) partials merged by attn_combine_kernel.
// SPLIT=0 fallback: grid (32,16,1), whole KV range per block (round-10 behavior).
template <int SPLIT>
__global__ __launch_bounds__(256) void attn_kernel(const unsigned short* __restrict__ qk,
                                                   const unsigned short* __restrict__ vT,
                                                   unsigned short* __restrict__ y,
                                                   float* __restrict__ opart,
                                                   float* __restrict__ mlpart) {
  int qblk = blockIdx.x;
  int h = blockIdx.y;
  int z = SPLIT ? blockIdx.z : 0;
  int ntiles = qblk + 1;
  int t0 = z * 8;
  if (SPLIT && t0 >= ntiles) return;
  int t1 = SPLIT ? (t0 + 8 < ntiles ? t0 + 8 : ntiles) : ntiles;
  int ns = SPLIT ? ((qblk + 8) >> 3) : 1;
  int wv = threadIdx.x >> 6;
  int lane = threadIdx.x & 63;
  int qbase = qblk * 64 + wv * 16;

  __shared__ __align__(16) unsigned short Ks[2 * 4096];  // [buf][key][64 d] swz
  __shared__ __align__(16) unsigned short Vs[2 * 4096];  // [buf][d][64 key] swz
  __shared__ __align__(16) unsigned short ps[4][16 * 72];

  const int c0 = wv * 64 + lane;
  const int r0 = c0 >> 3,         k0 = (c0 & 7) ^ (r0 & 7);
  const int r1 = (c0 + 256) >> 3, k1 = (c0 & 7) ^ (r1 & 7);
  unsigned short* kd0 = Ks + wv * 512;
  unsigned short* kd1 = Ks + 2048 + wv * 512;
  unsigned short* vd0 = Vs + wv * 512;
  unsigned short* vd1 = Vs + 2048 + wv * 512;
  const unsigned short* kgp0 = qk + 1024 + h * 64 + k0 * 8 + (size_t)r0 * 2048;
  const unsigned short* kgp1 = qk + 1024 + h * 64 + k1 * 8 + (size_t)r1 * 2048;
  const unsigned short* vgp0 = vT + (size_t)(h * 64 + r0) * 2048 + k0 * 8;
  const unsigned short* vgp1 = vT + (size_t)(h * 64 + r1) * 2048 + k1 * 8;
  auto stage = [&](int buf, int j0) {
    int bo = buf * 4096;
    gl16(kgp0 + (size_t)j0 * 2048, kd0 + bo);
    gl16(kgp1 + (size_t)j0 * 2048, kd1 + bo);
    gl16(vgp0 + j0, vd0 + bo);
    gl16(vgp1 + j0, vd1 + bo);
  };

  short8 qa[2];
  {
    int m = lane & 15, dj = (lane >> 4) * 8;
    const unsigned short* qp = qk + (size_t)(qbase + m) * 2048 + h * 64 + dj;
    qa[0] = *(const short8*)(qp);
    qa[1] = *(const short8*)(qp + 32);
  }
  floatx4 o[4] = {};
  float mrow[4] = {-1e30f, -1e30f, -1e30f, -1e30f};
  float lrow[4] = {0.f, 0.f, 0.f, 0.f};

  stage(0, t0 * 64);
  FBAR();
  for (int tile = t0; tile < t1; ++tile) {
    int j0 = tile * 64;
    int ti = tile - t0;
    if (tile + 1 < t1) stage((ti + 1) & 1, j0 + 64);
    const unsigned short* Kb = Ks + (ti & 1) * 4096;
    const unsigned short* Vb = Vs + (ti & 1) * 4096;
    floatx4 sacc[4];
    #pragma unroll
    for (int kg = 0; kg < 4; ++kg) {
      floatx4 zz = {0.f, 0.f, 0.f, 0.f};
      #pragma unroll
      for (int kc = 0; kc < 2; ++kc) {
        int kr = kg * 16 + (lane & 15);
        int p = (kc * 4 + (lane >> 4)) ^ (kr & 7);
        short8 kb = *(const short8*)(Kb + kr * 64 + p * 8);
        zz = __builtin_amdgcn_mfma_f32_16x16x32_bf16(qa[kc], kb, zz, 0, 0, 0);
      }
      sacc[kg] = zz;
    }
    // causal mask only on the diagonal tile (wave-uniform branch)
    if (tile == qblk) {
      #pragma unroll
      for (int kg = 0; kg < 4; ++kg)
        #pragma unroll
        for (int r = 0; r < 4; ++r) {
          int key_g = j0 + kg * 16 + (lane & 15);
          int q_g = qbase + (lane >> 4) * 4 + r;
          float s = sacc[kg][r] * 0.125f;
          sacc[kg][r] = (key_g <= q_g) ? s : -1e30f;
        }
    } else {
      #pragma unroll
      for (int kg = 0; kg < 4; ++kg)
        #pragma unroll
        for (int r = 0; r < 4; ++r) sacc[kg][r] *= 0.125f;
    }
    #pragma unroll
    for (int r = 0; r < 4; ++r) {
      float mx = fmaxf(fmaxf(sacc[0][r], sacc[1][r]), fmaxf(sacc[2][r], sacc[3][r]));
      mx = fmaxf(mx, __shfl_xor(mx, 1, 64));
      mx = fmaxf(mx, __shfl_xor(mx, 2, 64));
      mx = fmaxf(mx, __shfl_xor(mx, 4, 64));
      mx = fmaxf(mx, __shfl_xor(mx, 8, 64));
      float mnew = fmaxf(mrow[r], mx);
      float al = __expf(mrow[r] - mnew);
      mrow[r] = mnew;
      float sum = 0.f;
      #pragma unroll
      for (int kg = 0; kg < 4; ++kg) {
        float p = __expf(sacc[kg][r] - mnew);
        sacc[kg][r] = p;
        sum += p;
      }
      sum += __shfl_xor(sum, 1, 64);
      sum += __shfl_xor(sum, 2, 64);
      sum += __shfl_xor(sum, 4, 64);
      sum += __shfl_xor(sum, 8, 64);
      lrow[r] = lrow[r] * al + sum;
      #pragma unroll
      for (int ni = 0; ni < 4; ++ni) o[ni][r] *= al;
    }
    unsigned short* pw = ps[wv];
    #pragma unroll
    for (int kg = 0; kg < 4; ++kg)
      #pragma unroll
      for (int r = 0; r < 4; ++r)
        pw[((lane >> 4) * 4 + r) * 72 + kg * 16 + (lane & 15)] = f2bf(sacc[kg][r]);
    asm volatile("s_waitcnt lgkmcnt(0)" ::: "memory");
    short8 pa[2];
    pa[0] = *(const short8*)(pw + (lane & 15) * 72 + (lane >> 4) * 8);
    pa[1] = *(const short8*)(pw + (lane & 15) * 72 + 32 + (lane >> 4) * 8);
    #pragma unroll
    for (int ni = 0; ni < 4; ++ni) {
      floatx4 zz = o[ni];
      int dd = ni * 16 + (lane & 15);
      #pragma unroll
      for (int kc = 0; kc < 2; ++kc) {
        int p = (kc * 4 + (lane >> 4)) ^ (dd & 7);
        short8 vb = *(const short8*)(Vb + dd * 64 + p * 8);
        zz = __builtin_amdgcn_mfma_f32_16x16x32_bf16(pa[kc], vb, zz, 0, 0, 0);
      }
      o[ni] = zz;
    }
    if (tile + 1 < t1) FBAR();
  }

  if (ns == 1) {
    #pragma unroll
    for (int ni = 0; ni < 4; ++ni)
      #pragma unroll
      for (int r = 0; r < 4; ++r) {
        int q = qbase + (lane >> 4) * 4 + r;
        int dd = ni * 16 + (lane & 15);
        y[(size_t)q * 1024 + h * 64 + dd] = f2bf(o[ni][r] / lrow[r]);
      }
  } else {
    float* op = opart + ((size_t)((qblk << 4) + h) * 4 + z) * 4096;
    #pragma unroll
    for (int ni = 0; ni < 4; ++ni)
      #pragma unroll
      for (int r = 0; r < 4; ++r) {
        int row = wv * 16 + (lane >> 4) * 4 + r;
        int col = ni * 16 + (lane & 15);
        op[row * 64 + col] = o[ni][r];
      }
    float* mlp = mlpart + ((size_t)((qblk << 4) + h) * 4 + z) * 128;
    if ((lane & 15) == 0) {
      #pragma unroll
      for (int r = 0; r < 4; ++r) {
        int row = wv * 16 + (lane >> 4) * 4 + r;
        mlp[row] = mrow[r];
        mlp[64 + row] = lrow[r];
      }
    }
  }
}

// ---------- attn slice combine: y = (sum_z w_z O_z) / (sum_z w_z l_z) ----------
__global__ __launch_bounds__(256) void attn_combine_kernel(const float* __restrict__ opart,
                                                           const float* __restrict__ mlpart,
                                                           unsigned short* __restrict__ y) {
  int g = blockIdx.x;          // qblk*16 + h
  int qblk = g >> 4, h = g & 15;
  int ns = (qblk + 8) >> 3;    // ceil((qblk+1)/8)
  if (ns < 2) return;          // slice 0 wrote y directly
  int row = threadIdx.x >> 2;
  int col0 = (threadIdx.x & 3) << 4;
  const float* mlg = mlpart + (size_t)g * 512;
  float m0v = mlg[row],       l0v = mlg[64 + row];
  float m1v = mlg[128 + row], l1v = mlg[192 + row];
  float m2v = (ns > 2) ? mlg[256 + row] : -1e30f;
  float l2v = (ns > 2) ? mlg[320 + row] : 0.f;
  float m3v = (ns > 3) ? mlg[384 + row] : -1e30f;
  float l3v = (ns > 3) ? mlg[448 + row] : 0.f;
  float M = fmaxf(fmaxf(m0v, m1v), fmaxf(m2v, m3v));
  float w0 = __expf(m0v - M), w1 = __expf(m1v - M);
  float w2 = (ns > 2) ? __expf(m2v - M) : 0.f;
  float w3 = (ns > 3) ? __expf(m3v - M) : 0.f;
  float inv = 1.0f / (w0 * l0v + w1 * l1v + w2 * l2v + w3 * l3v);
  const float* og = opart + (size_t)g * 16384 + row * 64 + col0;
  unsigned short* yp = y + (size_t)(qblk * 64 + row) * 1024 + h * 64 + col0;
  #pragma unroll
  for (int j = 0; j < 16; j += 4) {
    float4 v0 = *(const float4*)(og + j);
    float4 v1 = *(const float4*)(og + 4096 + j);
    float ax = w0 * v0.x + w1 * v1.x;
    float ay = w0 * v0.y + w1 * v1.y;
    float az = w0 * v0.z + w1 * v1.z;
    float aw = w0 * v0.w + w1 * v1.w;
    if (ns > 2) {
      float4 v2 = *(const float4*)(og + 8192 + j);
      ax += w2 * v2.x; ay += w2 * v2.y; az += w2 * v2.z; aw += w2 * v2.w;
    }
    if (ns > 3) {
      float4 v3 = *(const float4*)(og + 12288 + j);
      ax += w3 * v3.x; ay += w3 * v3.y; az += w3 * v3.z; aw += w3 * v3.w;
    }
    ushortx4 o4;
    o4[0] = f2bf(ax * inv); o4[1] = f2bf(ay * inv);
    o4[2] = f2bf(az * inv); o4[3] = f2bf(aw * inv);
    *(ushortx4*)(yp + j) = o4;
  }
}

extern "C" void kernel_launch(void* const* d_in, const int* in_sizes, int n_in,
                              void* d_out, int out_size, void* d_ws, size_t ws_size,
                              hipStream_t stream) {
  const int L = 1536, S = 512, D = 1024, T = 2048, FF = 4096;
  const void* x        = d_in[0];
  const void* c        = d_in[1];
  const void* freqs    = d_in[2];
  const void* px_qk_w  = d_in[3];
  const void* px_qn    = d_in[4];
  const void* px_kn    = d_in[5];
  const void* px_v_w   = d_in[6];
  const void* px_v_b   = d_in[7];
  const void* pc_qk_w  = d_in[8];
  const void* pc_qn    = d_in[9];
  const void* pc_kn    = d_in[10];
  const void* pc_v_w   = d_in[11];
  const void* pc_v_b   = d_in[12];
  const void* p1_proj_w = d_in[13];
  const void* p1_proj_b = d_in[14];
  const void* p1_w1 = d_in[15];
  const void* p1_b1 = d_in[16];
  const void* p1_w3 = d_in[17];
  const void* p1_b3 = d_in[18];
  const void* p1_w2 = d_in[19];
  const void* p1_b2 = d_in[20];
  const void* p2_proj_w = d_in[21];
  const void* p2_proj_b = d_in[22];
  const void* p2_w1 = d_in[23];
  const void* p2_b1 = d_in[24];
  const void* p2_w3 = d_in[25];
  const void* p2_b3 = d_in[26];
  const void* p2_w2 = d_in[27];
  const void* p2_b2 = d_in[28];

  // Workspace map (MB from ws):
  //  0-4   hln -> ybuf -> h1c        4-12 qk / h1x      12-16 vT / h1x
  //  16-20 mid   20-21 midln_c   21 flag   22-23 attn m/l partials
  //  24-40 bf16 cache: qk_c qk_x v_c v_x pj1 pj2   (convw_A)
  //  40-72 attn O partials (32MB) -> P2 partials -> convw_B w1/w3 -> P5 partials
  //  72-88 bf16 cache: w2p1 w2p2                   (convw_A)
  char* ws = (char*)d_ws;
  unsigned short* hln     = (unsigned short*)(ws);
  unsigned short* ybuf    = (unsigned short*)(ws);
  unsigned short* h1c     = (unsigned short*)(ws);
  unsigned short* qkbuf   = (unsigned short*)(ws + ((size_t)4  << 20));
  unsigned short* h1x     = (unsigned short*)(ws + ((size_t)4  << 20));
  unsigned short* vbufT   = (unsigned short*)(ws + ((size_t)12 << 20));
  unsigned short* mid     = (unsigned short*)(ws + ((size_t)16 << 20));
  unsigned short* midln_c = (unsigned short*)(ws + ((size_t)20 << 20));
  int*            flag    = (int*)(ws + ((size_t)21 << 20));
  float*          mlpart  = (float*)(ws + ((size_t)22 << 20));
  unsigned short* midln_x = (unsigned short*)d_out;
  unsigned short* hlnx    = hln + (size_t)S * D;

  const bool conv = ws_size >= ((size_t)90 << 20);
  unsigned short* wbf = (unsigned short*)(ws + ((size_t)24 << 20));
  unsigned short* b_qk_c = wbf + 0;
  unsigned short* b_qk_x = wbf + 2097152;
  unsigned short* b_v_c  = wbf + 4194304;
  unsigned short* b_v_x  = wbf + 5242880;
  unsigned short* b_pj1  = wbf + 6291456;
  unsigned short* b_pj2  = wbf + 7340032;
  unsigned short* b_w1p1 = wbf + 8388608;   // 40-48 MB
  unsigned short* b_w1p2 = wbf + 12582912;  // 48-56
  unsigned short* b_w3p1 = wbf + 16777216;  // 56-64
  unsigned short* b_w3p2 = wbf + 20971520;  // 64-72
  unsigned short* b_w2p1 = wbf + 25165824;  // 72-80
  unsigned short* b_w2p2 = wbf + 29360128;  // 80-88
  float* part  = (float*)(ws + ((size_t)40 << 20));  // 4x8MB (P2/P5 partials)
  float* opart = (float*)(ws + ((size_t)40 << 20));  // attn O partials (32MB)

  detect_kernel<<<1, 64, 0, stream>>>((const unsigned int*)px_qn, flag);

  if (conv) {
    // convw_A: everything except w1/w3 (whose cache region hosts attn/P2 partials first)
    CArgs ca = {};
    const void* insA[8]    = {pc_qk_w, px_qk_w, pc_v_w, px_v_w, p1_proj_w, p2_proj_w,
                              p1_w2, p2_w2};
    unsigned short* osA[8] = {b_qk_c, b_qk_x, b_v_c, b_v_x, b_pj1, b_pj2,
                              b_w2p1, b_w2p2};
    unsigned int cntA[8]   = {262144, 262144, 131072, 131072, 131072, 131072,
                              524288, 524288};
    unsigned int cum = 0;
    for (int i = 0; i < 8; ++i) { ca.in[i] = insA[i]; ca.out[i] = osA[i]; cum += cntA[i]; ca.cum[i] = cum; }
    for (int i = 8; i < 12; ++i) ca.cum[i] = 0x7FFFFFFFu;
    convw_kernel<<<1024, 256, 0, stream>>>(ca, flag);
  }

  ln_ext_kernel<<<T, 256, 0, stream>>>(c, x, hln, flag);

  // P1: QKV (4 descriptors). V descs (2,3) store TRANSPOSED into vbufT (tmask).
  {
    GArgs g = {};
    g.A[0] = hln;  g.bias[0] = nullptr; g.C[0] = qkbuf;                    g.mcum[0] = 4;  g.N[0] = 2048;
    g.A[1] = hlnx; g.bias[1] = nullptr; g.C[1] = qkbuf + (size_t)S * 2048; g.mcum[1] = 16; g.N[1] = 2048;
    g.A[2] = hln;  g.bias[2] = pc_v_b;  g.C[2] = vbufT; g.oo[2] = 0;       g.mcum[2] = 20; g.N[2] = 1024;
    g.A[3] = hlnx; g.bias[3] = px_v_b;  g.C[3] = vbufT; g.oo[3] = S;       g.mcum[3] = 32; g.N[3] = 1024;
    g.K = 1024; g.nd = 4; g.tmask = 0b1100;
    if (conv) {
      g.B[0] = b_qk_c; g.B[1] = b_qk_x; g.B[2] = b_v_c; g.B[3] = b_v_x;
      gemm_kernel<0, 0, 1, 1><<<dim3(16, 32), 256, 0, stream>>>(g, flag);
    } else {
      g.B[0] = pc_qk_w; g.B[1] = px_qk_w; g.B[2] = pc_v_w; g.B[3] = px_v_w;
      gemm_kernel<0, 0, 1, 0><<<dim3(16, 32), 256, 0, stream>>>(g, flag);
    }
  }
  rmsrope_kernel<<<dim3(T, 4), 256, 0, stream>>>(qkbuf, pc_qn, pc_kn, px_qn, px_kn, freqs, flag);
  if (conv) {
    attn_kernel<1><<<dim3(32, 16, 4), 256, 0, stream>>>(qkbuf, vbufT, ybuf, opart, mlpart);
    attn_combine_kernel<<<512, 256, 0, stream>>>(opart, mlpart, ybuf);
  } else {
    attn_kernel<0><<<dim3(32, 16, 1), 256, 0, stream>>>(qkbuf, vbufT, ybuf, opart, mlpart);
  }

  // P2: out-projection + external residual -> mid.
  if (conv) {
    GArgs g = {};
    g.A[0] = ybuf;                  g.C[0] = mid; g.oo[0] = 0;             g.bias[0] = p2_proj_b; g.res[0] = c; g.mcum[0] = 4;  g.N[0] = 1024;
    g.A[1] = ybuf + (size_t)S * D;  g.C[1] = mid; g.oo[1] = (size_t)S * D; g.bias[1] = p1_proj_b; g.res[1] = x; g.mcum[1] = 16; g.N[1] = 1024;
    g.K = 1024; g.nd = 2;
    g.part = part;
    g.B[0] = b_pj2; g.B[1] = b_pj1;
    gemm_kernel<1, 3, 4, 1><<<dim3(8, 16, 4), 256, 0, stream>>>(g, flag);
    reduce_mid_kernel<<<2048, 256, 0, stream>>>(part, c, x, (const float*)p2_proj_b,
                                                (const float*)p1_proj_b, mid, flag);
    // convw_B: w1/w3 into the region P2's partials just vacated
    CArgs cb = {};
    const void* insB[4]    = {p1_w1, p2_w1, p1_w3, p2_w3};
    unsigned short* osB[4] = {b_w1p1, b_w1p2, b_w3p1, b_w3p2};
    unsigned int cum = 0;
    for (int i = 0; i < 4; ++i) { cb.in[i] = insB[i]; cb.out[i] = osB[i]; cum += 524288u; cb.cum[i] = cum; }
    for (int i = 4; i < 12; ++i) cb.cum[i] = 0x7FFFFFFFu;
    convw_kernel<<<1024, 256, 0, stream>>>(cb, flag);
  } else {
    GArgs g = {};
    g.A[0] = ybuf;                  g.bias[0] = p2_proj_b; g.res[0] = c; g.C[0] = mid;                  g.mcum[0] = 4;  g.N[0] = 1024;
    g.A[1] = ybuf + (size_t)S * D;  g.bias[1] = p1_proj_b; g.res[1] = x; g.C[1] = mid + (size_t)S * D;  g.mcum[1] = 16; g.N[1] = 1024;
    g.K = 1024; g.nd = 2;
    g.B[0] = p2_proj_w; g.B[1] = p1_proj_w;
    gemm_kernel<1, 0, 1, 0><<<dim3(8, 16), 256, 0, stream>>>(g, flag);
  }
  ln_mid_kernel<<<T, 256, 0, stream>>>(mid, midln_c, midln_x);

  // P3: W1 (x + c merged)
  {
    GArgs g = {};
    g.A[0] = midln_x; g.bias[0] = p1_b1; g.C[0] = h1x; g.mcum[0] = 12; g.N[0] = 4096;
    g.A[1] = midln_c; g.bias[1] = p2_b1; g.C[1] = h1c; g.mcum[1] = 16; g.N[1] = 4096;
    g.K = 1024; g.nd = 2;
    if (conv) {
      g.B[0] = b_w1p1; g.B[1] = b_w1p2;
      gemm_kernel<0, 0, 1, 1><<<dim3(32, 16), 256, 0, stream>>>(g, flag);
    } else {
      g.B[0] = p1_w1; g.B[1] = p2_w1;
      gemm_kernel<0, 0, 1, 0><<<dim3(32, 16), 256, 0, stream>>>(g, flag);
    }
  }
  // P4: W3 with fused silu(h1)*(acc+bias), in place
  {
    GArgs g = {};
    g.A[0] = midln_x; g.bias[0] = p1_b3; g.res[0] = h1x; g.C[0] = h1x; g.mcum[0] = 12; g.N[0] = 4096;
    g.A[1] = midln_c; g.bias[1] = p2_b3; g.res[1] = h1c; g.C[1] = h1c; g.mcum[1] = 16; g.N[1] = 4096;
    g.K = 1024; g.nd = 2;
    if (conv) {
      g.B[0] = b_w3p1; g.B[1] = b_w3p2;
      gemm_kernel<3, 0, 1, 1><<<dim3(32, 16), 256, 0, stream>>>(g, flag);
    } else {
      g.B[0] = p1_w3; g.B[1] = p2_w3;
      gemm_kernel<3, 0, 1, 0><<<dim3(32, 16), 256, 0, stream>>>(g, flag);
    }
  }
  // P5: W2 split-K=4. conv: raw fp32 partials + reduce. fallback: zero + atomics.
  if (conv) {
    GArgs g = {};
    g.A[0] = h1x; g.bias[0] = p1_b2; g.res[0] = mid + (size_t)S * D; g.C[0] = d_out; g.oo[0] = 0;             g.mcum[0] = 12; g.N[0] = 1024;
    g.A[1] = h1c; g.bias[1] = p2_b2; g.res[1] = mid;                 g.C[1] = d_out; g.oo[1] = (size_t)L * D; g.mcum[1] = 16; g.N[1] = 1024;
    g.K = 4096; g.nd = 2;
    g.part = part;
    g.B[0] = b_w2p1; g.B[1] = b_w2p2;
    gemm_kernel<4, 3, 4, 1><<<dim3(8, 16, 4), 256, 0, stream>>>(g, flag);
    reduce_kernel<<<2048, 256, 0, stream>>>(part, mid, p1_b2, p2_b2, (float*)d_out, flag);
  } else {
    zero_kernel<<<2048, 256, 0, stream>>>(d_out, out_size, flag);
    GArgs g = {};
    g.A[0] = h1x; g.bias[0] = p1_b2; g.res[0] = mid + (size_t)S * D; g.C[0] = d_out; g.oo[0] = 0;             g.mcum[0] = 12; g.N[0] = 1024;
    g.A[1] = h1c; g.bias[1] = p2_b2; g.res[1] = mid;                 g.C[1] = d_out; g.oo[1] = (size_t)L * D; g.mcum[1] = 16; g.N[1] = 1024;
    g.K = 4096; g.nd = 2;
    g.B[0] = p1_w2; g.B[1] = p2_w2;
    gemm_kernel<4, 2, 4, 0><<<dim3(8, 16, 4), 256, 0, stream>>>(g, flag);
  }
}